// Round 3
// baseline (271.275 us; speedup 1.0000x reference)
//
#include <hip/hip_runtime.h>
#include <math.h>

#define H 256
#define W 256
#define HW (H * W)
#define B 2
#define V 3
#define BV (B * V)
#define C 32
#define RADIUS 1.5f
#define TAU 1.0f
#define EPS 1e-8f

#define NPIX (BV * HW)    // 393216 destination pixels (= source points)
#define NBLK (NPIX / 256) // 1536 (divisible by 8 -> bijective XCD swizzle)

// Cell grid: one bin per ROUNDED projected position, 1-pixel halo.
#define GW 258
#define GH 258
#define NCELL (BV * GH * GW)          // 399384 cells
#define NALLOC_BLK ((NCELL + 255) / 256)

// XCD-aware chunked swizzle (NBLK divisible by 8 -> bijective).
__device__ __forceinline__ int swizzle_block(int bid) {
    return (bid & 7) * (NBLK / 8) + (bid >> 3);
}

// ---------------------------------------------------------------------------
// Setup: per (b,v) fold the projection chain into one matrix
//   M = K[b] * dst_RT[b] * src_RTinv[b,v] * inv(K[b])
// ---------------------------------------------------------------------------
__global__ void setup_kernel(const float* __restrict__ Kmat,
                             const float* __restrict__ srcRTinv,
                             const float* __restrict__ dstRT,
                             float* __restrict__ Mbuf) {
    int bv = threadIdx.x;
    if (bv >= BV) return;
    int b = bv / V;

    float a[4][8];
    for (int i = 0; i < 4; i++)
        for (int j = 0; j < 4; j++) {
            a[i][j] = Kmat[b * 16 + i * 4 + j];
            a[i][4 + j] = (i == j) ? 1.0f : 0.0f;
        }
    for (int col = 0; col < 4; col++) {
        int piv = col;
        float best = fabsf(a[col][col]);
        for (int r = col + 1; r < 4; r++) {
            float v = fabsf(a[r][col]);
            if (v > best) { best = v; piv = r; }
        }
        if (piv != col) {
            for (int j = 0; j < 8; j++) {
                float t = a[col][j]; a[col][j] = a[piv][j]; a[piv][j] = t;
            }
        }
        float s = 1.0f / a[col][col];
        for (int j = 0; j < 8; j++) a[col][j] *= s;
        for (int r = 0; r < 4; r++) {
            if (r == col) continue;
            float m = a[r][col];
            for (int j = 0; j < 8; j++) a[r][j] -= m * a[col][j];
        }
    }
    float Kinv[16];
    for (int i = 0; i < 4; i++)
        for (int j = 0; j < 4; j++) Kinv[i * 4 + j] = a[i][4 + j];

    float T1[16];
    const float* S = srcRTinv + bv * 16;
    for (int i = 0; i < 4; i++)
        for (int j = 0; j < 4; j++) {
            float acc = 0.0f;
            for (int k = 0; k < 4; k++) acc += S[i * 4 + k] * Kinv[k * 4 + j];
            T1[i * 4 + j] = acc;
        }
    float T2[16];
    const float* D = dstRT + b * 16;
    for (int i = 0; i < 4; i++)
        for (int j = 0; j < 4; j++) {
            float acc = 0.0f;
            for (int k = 0; k < 4; k++) acc += D[i * 4 + k] * T1[k * 4 + j];
            T2[i * 4 + j] = acc;
        }
    const float* Kb = Kmat + b * 16;
    for (int i = 0; i < 4; i++)
        for (int j = 0; j < 4; j++) {
            float acc = 0.0f;
            for (int k = 0; k < 4; k++) acc += Kb[i * 4 + k] * T2[k * 4 + j];
            Mbuf[bv * 16 + i * 4 + j] = acc;
        }
}

// ---------------------------------------------------------------------------
// Shared projection/filter (count and fill MUST be bit-identical).
// Returns false iff the point contributes 0 to every in-image tap.
// ---------------------------------------------------------------------------
__device__ __forceinline__ bool proj_cell(int gid,
                                          const float* __restrict__ depths,
                                          const float* __restrict__ Mbuf,
                                          float& px, float& py, float& z,
                                          int& cell, int& n) {
    int bv = gid >> 16;
    n = gid & (HW - 1);
    float xn = (float)(n & (W - 1)) * (2.0f / (W - 1)) - 1.0f;
    float yn = (float)(n >> 8)      * (2.0f / (H - 1)) - 1.0f;
    float d = depths[gid];
    const float* M = Mbuf + bv * 16;
    float X = xn * d, Y = yn * d;
    float p0 = M[0] * X + M[1] * Y + M[2] * d + M[3];
    float p1 = M[4] * X + M[5] * Y + M[6] * d + M[7];
    z = M[8] * X + M[9] * Y + M[10] * d + M[11];
    if (!(z > 0.0f)) return false;  // reference masks z<=0 taps entirely
    float inv = 1.0f / (z + EPS);
    px = (p0 * inv + 1.0f) * 0.5f * (float)(W - 1);
    py = (p1 * inv + 1.0f) * 0.5f * (float)(H - 1);
    float rx = rintf(px), ry = rintf(py);
    // rounding outside the 1-px halo -> no in-image tap with weight > 0
    if (rx < -1.0f || rx > (float)W || ry < -1.0f || ry > (float)H) return false;
    cell = bv * (GH * GW) + ((int)ry + 1) * GW + ((int)rx + 1);
    return true;
}

// ---------------------------------------------------------------------------
// CSR pass 1: count points per cell (meta[cell].y).
// ---------------------------------------------------------------------------
__global__ __launch_bounds__(256) void count_kernel(
    const float* __restrict__ depths, const float* __restrict__ Mbuf,
    int2* __restrict__ meta) {
    int gid = swizzle_block(blockIdx.x) * 256 + threadIdx.x;
    float px, py, z; int cell, n;
    if (!proj_cell(gid, depths, Mbuf, px, py, z, cell, n)) return;
    atomicAdd(&meta[cell].y, 1);
}

// ---------------------------------------------------------------------------
// CSR pass 2: exclusive-scan alloc. Block-local scan (shfl wave scan +
// cross-wave LDS) then ONE atomic per block on the global cursor; cells of
// one block get a contiguous region -> entries stay spatially clustered.
// meta[cell].x = exclusive start offset.
// ---------------------------------------------------------------------------
__global__ __launch_bounds__(256) void alloc_kernel(int2* __restrict__ meta,
                                                    int* __restrict__ total) {
    int i = blockIdx.x * 256 + threadIdx.x;
    int c = (i < NCELL) ? meta[i].y : 0;
    int lane = threadIdx.x & 63;
    int wid = threadIdx.x >> 6;
    int x = c;  // inclusive scan within wave
#pragma unroll
    for (int dlt = 1; dlt < 64; dlt <<= 1) {
        int y = __shfl_up(x, dlt);
        if (lane >= dlt) x += y;
    }
    __shared__ int wsum[4];
    __shared__ int wbase[4];
    __shared__ int bbase;
    if (lane == 63) wsum[wid] = x;
    __syncthreads();
    if (threadIdx.x == 0) {
        int s0 = wsum[0], s1 = wsum[1], s2 = wsum[2], s3 = wsum[3];
        wbase[0] = 0; wbase[1] = s0; wbase[2] = s0 + s1; wbase[3] = s0 + s1 + s2;
        bbase = atomicAdd(total, s0 + s1 + s2 + s3);
    }
    __syncthreads();
    if (i < NCELL) meta[i].x = bbase + wbase[wid] + (x - c);
}

// ---------------------------------------------------------------------------
// CSR pass 3: fill. Recompute projection (bit-identical to count) and write
// the finished per-point record {px,py,z,n} ONCE. After this pass
// meta[cell].x == end of the cell's range (start = end - cnt).
// ---------------------------------------------------------------------------
__global__ __launch_bounds__(256) void fill_kernel(
    const float* __restrict__ depths, const float* __restrict__ Mbuf,
    int2* __restrict__ meta, float4* __restrict__ entries) {
    int gid = swizzle_block(blockIdx.x) * 256 + threadIdx.x;
    float px, py, z; int cell, n;
    if (!proj_cell(gid, depths, Mbuf, px, py, z, cell, n)) return;
    int pos = atomicAdd(&meta[cell].x, 1);
    entries[pos] = make_float4(px, py, z, __uint_as_float((unsigned int)n));
}

// ---------------------------------------------------------------------------
// Transpose feats (BV,C,HW) -> featsT (BV,HW,C), both fp32: one contiguous
// 128B record per point (f32 keeps gather cvt-free and improves absmax).
// ---------------------------------------------------------------------------
__global__ __launch_bounds__(256) void transpose_kernel(
    const float* __restrict__ feats, float* __restrict__ featsT) {
    __shared__ float sm[C][257];
    int blk = blockIdx.x;
    int bv = blk >> 8;
    int n0 = (blk & 255) << 8;
    int tid = threadIdx.x;
    const float* src = feats + (size_t)bv * C * HW + n0;
#pragma unroll
    for (int c = 0; c < C; c++) sm[c][tid] = src[(size_t)c * HW + tid];
    __syncthreads();
    float* dst = featsT + ((size_t)bv * HW + n0) * C;
#pragma unroll
    for (int pass = 0; pass < 8; pass++) {
        int nl = pass * 32 + (tid >> 3);
        int c4 = (tid & 7) << 2;
        float4 v = make_float4(sm[c4][nl], sm[c4 + 1][nl],
                               sm[c4 + 2][nl], sm[c4 + 3][nl]);
        *(float4*)(dst + (size_t)nl * C + c4) = v;
    }
}

// ---------------------------------------------------------------------------
// Phase 2: gather. One thread per dest pixel q; scan the 3x3 cell
// neighborhood on the halo grid (exactly the reference tap set). Per cell:
// one 8B meta load; per entry: one 16B load, 5-op distance test; per
// accepted tap: weight (sqrt+exp) + 8x float4 feature FMA. No projection
// recompute, no half->float cvt.
// ---------------------------------------------------------------------------
__global__ __launch_bounds__(256) void gather_kernel(
    const float* __restrict__ featsT, const int2* __restrict__ meta,
    const float4* __restrict__ entries, float* __restrict__ out) {
    int gid = swizzle_block(blockIdx.x) * 256 + threadIdx.x;
    int bv = gid >> 16;
    int q = gid & (HW - 1);
    float qx = (float)(q & (W - 1));
    float qy = (float)(q >> 8);

    const float* fb = featsT + ((size_t)bv << 16) * C;

    float wsum = 0.0f, zwsum = 0.0f;
    float facc[C];
#pragma unroll
    for (int c = 0; c < C; c++) facc[c] = 0.0f;

    // dest rows qy-1..qy+1 -> halo rows qy+dy; cols qx-1..qx+1 -> qx+dx
    int cbase = bv * (GH * GW);
#pragma unroll
    for (int dy = 0; dy < 3; dy++) {
        int rowbase = cbase + ((q >> 8) + dy) * GW + (q & (W - 1));
#pragma unroll
        for (int dx = 0; dx < 3; dx++) {
            int2 m2 = meta[rowbase + dx];
            int cnt = m2.y;
            const float4* e = entries + (m2.x - cnt);
            for (int j = 0; j < cnt; j++) {
                float4 v = e[j];
                float ddx = qx - v.x, ddy = qy - v.y;
                float d2 = ddx * ddx + ddy * ddy + EPS;
                if (d2 < RADIUS * RADIUS) {
                    float dist = sqrtf(d2);
                    float wr = fmaxf(0.0f, 1.0f - dist * (1.0f / RADIUS));
                    float w = wr * expf(-TAU * v.z);
                    wsum += w;
                    zwsum += v.z * w;
                    int n = (int)__float_as_uint(v.w);
                    const float4* fp = (const float4*)(fb + (size_t)n * C);
#pragma unroll
                    for (int g = 0; g < 8; g++) {
                        float4 f = fp[g];
                        facc[g * 4 + 0] = fmaf(w, f.x, facc[g * 4 + 0]);
                        facc[g * 4 + 1] = fmaf(w, f.y, facc[g * 4 + 1]);
                        facc[g * 4 + 2] = fmaf(w, f.z, facc[g * 4 + 2]);
                        facc[g * 4 + 3] = fmaf(w, f.w, facc[g * 4 + 3]);
                    }
                }
            }
        }
    }

    float invw = 1.0f / (wsum + EPS);
    float* ob = out + (size_t)bv * C * HW + q;
#pragma unroll
    for (int c = 0; c < C; c++) ob[(size_t)c * HW] = facc[c] * invw;
    out[(size_t)BV * C * HW + gid] = zwsum * invw;
}

extern "C" void kernel_launch(void* const* d_in, const int* in_sizes, int n_in,
                              void* d_out, int out_size, void* d_ws, size_t ws_size,
                              hipStream_t stream) {
    const float* depths   = (const float*)d_in[0];  // (B,V,1,H,W)
    const float* feats    = (const float*)d_in[1];  // (B,V,C,H,W)
    const float* Kmat     = (const float*)d_in[2];  // (B,4,4)
    const float* srcRTinv = (const float*)d_in[4];  // (B,V,4,4)
    const float* dstRT    = (const float*)d_in[5];  // (B,1,4,4)
    float* out = (float*)d_out;

    // ws layout:
    //   featsT  : NPIX*C float                 50.33 MB
    //   entries : NPIX float4 (exact CSR)       6.29 MB
    //   meta    : NCELL int2 {ofs,cnt}          3.20 MB (+16B total counter)
    //   Mbuf    : BV*16 float                   tiny
    // total ~59.8 MB (<= 63 MB proven available)
    char* ws = (char*)d_ws;
    size_t off_featsT = 0;
    size_t off_entries = off_featsT + (size_t)NPIX * C * 4;
    size_t off_meta = off_entries + (size_t)NPIX * 16;
    size_t off_total = off_meta + (size_t)NCELL * 8;
    size_t off_M = off_total + 16;
    size_t needed = off_M + (size_t)BV * 16 * 4;

    if (ws_size < needed) {
        hipMemsetAsync(d_out, 0, (size_t)out_size * 4, stream);
        return;
    }

    float* featsT   = (float*)(ws + off_featsT);
    float4* entries = (float4*)(ws + off_entries);
    int2* meta      = (int2*)(ws + off_meta);
    int* total      = (int*)(ws + off_total);
    float* Mbuf     = (float*)(ws + off_M);

    // zero meta {ofs,cnt} + global cursor in one memset (adjacent)
    hipMemsetAsync(meta, 0, (size_t)NCELL * 8 + 16, stream);
    setup_kernel<<<1, 64, 0, stream>>>(Kmat, srcRTinv, dstRT, Mbuf);
    count_kernel<<<NBLK, 256, 0, stream>>>(depths, Mbuf, meta);
    alloc_kernel<<<NALLOC_BLK, 256, 0, stream>>>(meta, total);
    fill_kernel<<<NBLK, 256, 0, stream>>>(depths, Mbuf, meta, entries);
    transpose_kernel<<<NBLK, 256, 0, stream>>>(feats, featsT);
    gather_kernel<<<NBLK, 256, 0, stream>>>(featsT, meta, entries, out);
}

// Round 4
// 220.677 us; speedup vs baseline: 1.2293x; 1.2293x over previous
//
#include <hip/hip_runtime.h>
#include <hip/hip_fp16.h>
#include <math.h>

#define H 256
#define W 256
#define HW (H * W)
#define B 2
#define V 3
#define BV (B * V)
#define C 32
#define RADIUS 1.5f
#define TAU 1.0f
#define EPS 1e-8f

#define NPIX (BV * HW)    // 393216 destination pixels (= source points)
#define NBLK (NPIX / 256) // 1536 (divisible by 8 -> bijective XCD swizzle)

// Cell grid: one bin per ROUNDED projected position, 1-pixel halo.
#define GW 258
#define GH 258
#define NCELL (BV * GH * GW)          // 399384 cells
#define NALLOC_BLK ((NCELL + 255) / 256)

// XCD-aware chunked swizzle (NBLK divisible by 8 -> bijective).
__device__ __forceinline__ int swizzle_block(int bid) {
    return (bid & 7) * (NBLK / 8) + (bid >> 3);
}

// ---------------------------------------------------------------------------
// Setup: per (b,v) fold the projection chain into one matrix
//   M = K[b] * dst_RT[b] * src_RTinv[b,v] * inv(K[b])
// ---------------------------------------------------------------------------
__global__ void setup_kernel(const float* __restrict__ Kmat,
                             const float* __restrict__ srcRTinv,
                             const float* __restrict__ dstRT,
                             float* __restrict__ Mbuf) {
    int bv = threadIdx.x;
    if (bv >= BV) return;
    int b = bv / V;

    float a[4][8];
    for (int i = 0; i < 4; i++)
        for (int j = 0; j < 4; j++) {
            a[i][j] = Kmat[b * 16 + i * 4 + j];
            a[i][4 + j] = (i == j) ? 1.0f : 0.0f;
        }
    for (int col = 0; col < 4; col++) {
        int piv = col;
        float best = fabsf(a[col][col]);
        for (int r = col + 1; r < 4; r++) {
            float v = fabsf(a[r][col]);
            if (v > best) { best = v; piv = r; }
        }
        if (piv != col) {
            for (int j = 0; j < 8; j++) {
                float t = a[col][j]; a[col][j] = a[piv][j]; a[piv][j] = t;
            }
        }
        float s = 1.0f / a[col][col];
        for (int j = 0; j < 8; j++) a[col][j] *= s;
        for (int r = 0; r < 4; r++) {
            if (r == col) continue;
            float m = a[r][col];
            for (int j = 0; j < 8; j++) a[r][j] -= m * a[col][j];
        }
    }
    float Kinv[16];
    for (int i = 0; i < 4; i++)
        for (int j = 0; j < 4; j++) Kinv[i * 4 + j] = a[i][4 + j];

    float T1[16];
    const float* S = srcRTinv + bv * 16;
    for (int i = 0; i < 4; i++)
        for (int j = 0; j < 4; j++) {
            float acc = 0.0f;
            for (int k = 0; k < 4; k++) acc += S[i * 4 + k] * Kinv[k * 4 + j];
            T1[i * 4 + j] = acc;
        }
    float T2[16];
    const float* D = dstRT + b * 16;
    for (int i = 0; i < 4; i++)
        for (int j = 0; j < 4; j++) {
            float acc = 0.0f;
            for (int k = 0; k < 4; k++) acc += D[i * 4 + k] * T1[k * 4 + j];
            T2[i * 4 + j] = acc;
        }
    const float* Kb = Kmat + b * 16;
    for (int i = 0; i < 4; i++)
        for (int j = 0; j < 4; j++) {
            float acc = 0.0f;
            for (int k = 0; k < 4; k++) acc += Kb[i * 4 + k] * T2[k * 4 + j];
            Mbuf[bv * 16 + i * 4 + j] = acc;
        }
}

// ---------------------------------------------------------------------------
// Pass 1: project + count. Writes ONE coalesced 16B staging record per point
// {px, py, z, cell_as_bits} (cell = -1 if the point can't touch any in-image
// tap) and bumps the cell count. No later pass ever reprojects: they COPY
// from staging, so count/fill are bit-identical by construction.
// ---------------------------------------------------------------------------
__global__ __launch_bounds__(256) void project_count_kernel(
    const float* __restrict__ depths, const float* __restrict__ Mbuf,
    float4* __restrict__ staging, int2* __restrict__ meta) {
    int gid = swizzle_block(blockIdx.x) * 256 + threadIdx.x;
    int bv = gid >> 16;
    int n = gid & (HW - 1);

    float xn = (float)(n & (W - 1)) * (2.0f / (W - 1)) - 1.0f;
    float yn = (float)(n >> 8)      * (2.0f / (H - 1)) - 1.0f;
    float d = depths[gid];
    const float* M = Mbuf + bv * 16;
    float X = xn * d, Y = yn * d;
    float p0 = M[0] * X + M[1] * Y + M[2] * d + M[3];
    float p1 = M[4] * X + M[5] * Y + M[6] * d + M[7];
    float z  = M[8] * X + M[9] * Y + M[10] * d + M[11];

    int cell = -1;
    float px = 0.0f, py = 0.0f;
    if (z > 0.0f) {  // reference masks z<=0 taps entirely
        float inv = 1.0f / (z + EPS);
        px = (p0 * inv + 1.0f) * 0.5f * (float)(W - 1);
        py = (p1 * inv + 1.0f) * 0.5f * (float)(H - 1);
        float rx = rintf(px), ry = rintf(py);
        // rounding outside the 1-px halo -> no in-image tap with weight > 0
        if (rx >= -1.0f && rx <= (float)W && ry >= -1.0f && ry <= (float)H) {
            cell = bv * (GH * GW) + ((int)ry + 1) * GW + ((int)rx + 1);
            atomicAdd(&meta[cell].y, 1);
        }
    }
    staging[gid] = make_float4(px, py, z, __int_as_float(cell));
}

// ---------------------------------------------------------------------------
// Pass 2: exclusive-scan alloc. Block-local scan (shfl wave scan + cross-wave
// LDS) then ONE atomic per block on the global cursor; cells of one block get
// a contiguous region -> entries stay spatially clustered.
// meta[cell].x = exclusive start offset.
// ---------------------------------------------------------------------------
__global__ __launch_bounds__(256) void alloc_kernel(int2* __restrict__ meta,
                                                    int* __restrict__ total) {
    int i = blockIdx.x * 256 + threadIdx.x;
    int c = (i < NCELL) ? meta[i].y : 0;
    int lane = threadIdx.x & 63;
    int wid = threadIdx.x >> 6;
    int x = c;  // inclusive scan within wave
#pragma unroll
    for (int dlt = 1; dlt < 64; dlt <<= 1) {
        int y = __shfl_up(x, dlt);
        if (lane >= dlt) x += y;
    }
    __shared__ int wsum[4];
    __shared__ int wbase[4];
    __shared__ int bbase;
    if (lane == 63) wsum[wid] = x;
    __syncthreads();
    if (threadIdx.x == 0) {
        int s0 = wsum[0], s1 = wsum[1], s2 = wsum[2], s3 = wsum[3];
        wbase[0] = 0; wbase[1] = s0; wbase[2] = s0 + s1; wbase[3] = s0 + s1 + s2;
        bbase = atomicAdd(total, s0 + s1 + s2 + s3);
    }
    __syncthreads();
    if (i < NCELL) meta[i].x = bbase + wbase[wid] + (x - c);
}

// ---------------------------------------------------------------------------
// Pass 3: fill (absorbs the transpose). Per block: LDS-stage a 256-point
// feats chunk (coalesced), then each thread copies its point's staging
// record to entries16[pos] = {px,py,z, wd=exp(-tau*z)} and writes the 64B
// fp16 feature record at entriesF[pos] (pos-indexed => gather needs NO
// n-indirection; cell-clustered => near-streaming reads).
// After this pass meta[cell].x == end of range (start = end - cnt).
// ---------------------------------------------------------------------------
__global__ __launch_bounds__(256) void fill_kernel(
    const float* __restrict__ feats, const float4* __restrict__ staging,
    int2* __restrict__ meta, float4* __restrict__ entries16,
    uint4* __restrict__ entriesF) {
    __shared__ float sm[C][257];
    int blk = blockIdx.x;
    int bv = blk >> 8;
    int n0 = (blk & 255) << 8;
    int tid = threadIdx.x;
    const float* src = feats + (size_t)bv * C * HW + n0;
#pragma unroll
    for (int c = 0; c < C; c++) sm[c][tid] = src[(size_t)c * HW + tid];
    __syncthreads();

    int gid = (bv << 16) | (n0 + tid);
    float4 s = staging[gid];
    int cell = __float_as_int(s.w);
    if (cell < 0) return;
    int pos = atomicAdd(&meta[cell].x, 1);

    float wd = expf(-TAU * s.z);  // once per point (was per tap in gather)
    entries16[pos] = make_float4(s.x, s.y, s.z, wd);

    // column read sm[c][tid]: bank (c + tid) % 32 -> 2 lanes/bank, free
    uint4* dst = entriesF + (size_t)pos * 4;
#pragma unroll
    for (int g = 0; g < 4; g++) {
        __half2 h0 = __floats2half2_rn(sm[g * 8 + 0][tid], sm[g * 8 + 1][tid]);
        __half2 h1 = __floats2half2_rn(sm[g * 8 + 2][tid], sm[g * 8 + 3][tid]);
        __half2 h2 = __floats2half2_rn(sm[g * 8 + 4][tid], sm[g * 8 + 5][tid]);
        __half2 h3 = __floats2half2_rn(sm[g * 8 + 6][tid], sm[g * 8 + 7][tid]);
        uint4 pk;
        pk.x = *(unsigned int*)&h0;
        pk.y = *(unsigned int*)&h1;
        pk.z = *(unsigned int*)&h2;
        pk.w = *(unsigned int*)&h3;
        dst[g] = pk;  // 64B record, 64B-aligned -> full-line writes
    }
}

// ---------------------------------------------------------------------------
// Pass 4: gather. One thread per dest pixel q; scan the 3x3 cell
// neighborhood on the halo grid (exactly the reference tap set). Per cell:
// one 8B meta load; per entry: 16B test load (contiguous within cell) +
// 5-op gate; per accepted tap: w = wr * wd (no exp, no reprojection) +
// 64B fp16 features at the SAME pos (no indirection) + 32 mixed FMA.
// ---------------------------------------------------------------------------
__global__ __launch_bounds__(256) void gather_kernel(
    const float4* __restrict__ entries16, const uint4* __restrict__ entriesF,
    const int2* __restrict__ meta, float* __restrict__ out) {
    int gid = swizzle_block(blockIdx.x) * 256 + threadIdx.x;
    int bv = gid >> 16;
    int q = gid & (HW - 1);
    float qx = (float)(q & (W - 1));
    float qy = (float)(q >> 8);

    float wsum = 0.0f, zwsum = 0.0f;
    float facc[C];
#pragma unroll
    for (int c = 0; c < C; c++) facc[c] = 0.0f;

    // dest rows qy-1..qy+1 -> halo rows qy+dy; cols qx-1..qx+1 -> qx+dx
    int cbase = bv * (GH * GW);
#pragma unroll
    for (int dy = 0; dy < 3; dy++) {
        int rowbase = cbase + ((q >> 8) + dy) * GW + (q & (W - 1));
#pragma unroll
        for (int dx = 0; dx < 3; dx++) {
            int2 m2 = meta[rowbase + dx];
            int cnt = m2.y;
            int pos0 = m2.x - cnt;
            for (int j = 0; j < cnt; j++) {
                float4 v = entries16[pos0 + j];
                float ddx = qx - v.x, ddy = qy - v.y;
                float d2 = ddx * ddx + ddy * ddy + EPS;
                if (d2 < RADIUS * RADIUS) {
                    float dist = sqrtf(d2);
                    float wr = fmaxf(0.0f, 1.0f - dist * (1.0f / RADIUS));
                    float w = wr * v.w;  // v.w = exp(-tau*z) precomputed
                    wsum += w;
                    zwsum += v.z * w;
                    const uint4* fp = entriesF + (size_t)(pos0 + j) * 4;
#pragma unroll
                    for (int g = 0; g < 4; g++) {
                        uint4 fv = fp[g];
                        const __half2* h2 = (const __half2*)&fv;
#pragma unroll
                        for (int k = 0; k < 4; k++) {
                            float2 f2 = __half22float2(h2[k]);
                            facc[g * 8 + 2 * k]     = fmaf(w, f2.x, facc[g * 8 + 2 * k]);
                            facc[g * 8 + 2 * k + 1] = fmaf(w, f2.y, facc[g * 8 + 2 * k + 1]);
                        }
                    }
                }
            }
        }
    }

    float invw = 1.0f / (wsum + EPS);
    float* ob = out + (size_t)bv * C * HW + q;
#pragma unroll
    for (int c = 0; c < C; c++) ob[(size_t)c * HW] = facc[c] * invw;
    out[(size_t)BV * C * HW + gid] = zwsum * invw;
}

extern "C" void kernel_launch(void* const* d_in, const int* in_sizes, int n_in,
                              void* d_out, int out_size, void* d_ws, size_t ws_size,
                              hipStream_t stream) {
    const float* depths   = (const float*)d_in[0];  // (B,V,1,H,W)
    const float* feats    = (const float*)d_in[1];  // (B,V,C,H,W)
    const float* Kmat     = (const float*)d_in[2];  // (B,4,4)
    const float* srcRTinv = (const float*)d_in[4];  // (B,V,4,4)
    const float* dstRT    = (const float*)d_in[5];  // (B,1,4,4)
    float* out = (float*)d_out;

    // ws layout:
    //   entriesF  : NPIX * 64B fp16 records (CSR pos-indexed)  25.17 MB
    //   entries16 : NPIX * float4 {px,py,z,wd}                  6.29 MB
    //   staging   : NPIX * float4 {px,py,z,cell}                6.29 MB
    //   meta      : NCELL int2 {ofs,cnt}                        3.20 MB (+16B)
    //   Mbuf      : BV*16 float                                 tiny
    // total ~41 MB (<= 63 MB proven available)
    char* ws = (char*)d_ws;
    size_t off_entriesF = 0;
    size_t off_entries16 = off_entriesF + (size_t)NPIX * 64;
    size_t off_staging = off_entries16 + (size_t)NPIX * 16;
    size_t off_meta = off_staging + (size_t)NPIX * 16;
    size_t off_total = off_meta + (size_t)NCELL * 8;
    size_t off_M = off_total + 16;
    size_t needed = off_M + (size_t)BV * 16 * 4;

    if (ws_size < needed) {
        hipMemsetAsync(d_out, 0, (size_t)out_size * 4, stream);
        return;
    }

    uint4* entriesF   = (uint4*)(ws + off_entriesF);
    float4* entries16 = (float4*)(ws + off_entries16);
    float4* staging   = (float4*)(ws + off_staging);
    int2* meta        = (int2*)(ws + off_meta);
    int* total        = (int*)(ws + off_total);
    float* Mbuf       = (float*)(ws + off_M);

    // zero meta {ofs,cnt} + global cursor in one memset (adjacent)
    hipMemsetAsync(meta, 0, (size_t)NCELL * 8 + 16, stream);
    setup_kernel<<<1, 64, 0, stream>>>(Kmat, srcRTinv, dstRT, Mbuf);
    project_count_kernel<<<NBLK, 256, 0, stream>>>(depths, Mbuf, staging, meta);
    alloc_kernel<<<NALLOC_BLK, 256, 0, stream>>>(meta, total);
    fill_kernel<<<NBLK, 256, 0, stream>>>(feats, staging, meta, entries16,
                                          entriesF);
    gather_kernel<<<NBLK, 256, 0, stream>>>(entries16, entriesF, meta, out);
}

// Round 6
// 183.932 us; speedup vs baseline: 1.4749x; 1.1998x over previous
//
#include <hip/hip_runtime.h>
#include <hip/hip_fp16.h>
#include <math.h>

#define H 256
#define W 256
#define HW (H * W)
#define B 2
#define V 3
#define BV (B * V)
#define C 32
#define RADIUS 1.5f
#define TAU 1.0f
#define EPS 1e-8f

#define NPIX (BV * HW)    // 393216 destination pixels (= source points)
#define NBLK (NPIX / 256) // 1536 (divisible by 8 -> bijective XCD swizzle)

// Cell grid: one bin per ROUNDED projected position, 1-pixel halo.
#define GW 258
#define GH 258
#define NCELL (BV * GH * GW)           // 399384 cells (+1 sentinel)
#define NSUMS ((NCELL + 255) / 256)    // 1561 alloc blocks
#define ROWCAP 64                      // staged entries per halo row (mean 16.4)

// XCD-aware chunked swizzle (NBLK divisible by 8 -> bijective).
__device__ __forceinline__ int swizzle_block(int bid) {
    return (bid & 7) * (NBLK / 8) + (bid >> 3);
}

// ---------------------------------------------------------------------------
// Setup: per (b,v) fold the projection chain into one matrix
//   M = K[b] * dst_RT[b] * src_RTinv[b,v] * inv(K[b])
// ---------------------------------------------------------------------------
__global__ void setup_kernel(const float* __restrict__ Kmat,
                             const float* __restrict__ srcRTinv,
                             const float* __restrict__ dstRT,
                             float* __restrict__ Mbuf) {
    int bv = threadIdx.x;
    if (bv >= BV) return;
    int b = bv / V;

    float a[4][8];
    for (int i = 0; i < 4; i++)
        for (int j = 0; j < 4; j++) {
            a[i][j] = Kmat[b * 16 + i * 4 + j];
            a[i][4 + j] = (i == j) ? 1.0f : 0.0f;
        }
    for (int col = 0; col < 4; col++) {
        int piv = col;
        float best = fabsf(a[col][col]);
        for (int r = col + 1; r < 4; r++) {
            float v = fabsf(a[r][col]);
            if (v > best) { best = v; piv = r; }
        }
        if (piv != col) {
            for (int j = 0; j < 8; j++) {
                float t = a[col][j]; a[col][j] = a[piv][j]; a[piv][j] = t;
            }
        }
        float s = 1.0f / a[col][col];
        for (int j = 0; j < 8; j++) a[col][j] *= s;
        for (int r = 0; r < 4; r++) {
            if (r == col) continue;
            float m = a[r][col];
            for (int j = 0; j < 8; j++) a[r][j] -= m * a[col][j];
        }
    }
    float Kinv[16];
    for (int i = 0; i < 4; i++)
        for (int j = 0; j < 4; j++) Kinv[i * 4 + j] = a[i][4 + j];

    float T1[16];
    const float* S = srcRTinv + bv * 16;
    for (int i = 0; i < 4; i++)
        for (int j = 0; j < 4; j++) {
            float acc = 0.0f;
            for (int k = 0; k < 4; k++) acc += S[i * 4 + k] * Kinv[k * 4 + j];
            T1[i * 4 + j] = acc;
        }
    float T2[16];
    const float* D = dstRT + b * 16;
    for (int i = 0; i < 4; i++)
        for (int j = 0; j < 4; j++) {
            float acc = 0.0f;
            for (int k = 0; k < 4; k++) acc += D[i * 4 + k] * T1[k * 4 + j];
            T2[i * 4 + j] = acc;
        }
    const float* Kb = Kmat + b * 16;
    for (int i = 0; i < 4; i++)
        for (int j = 0; j < 4; j++) {
            float acc = 0.0f;
            for (int k = 0; k < 4; k++) acc += Kb[i * 4 + k] * T2[k * 4 + j];
            Mbuf[bv * 16 + i * 4 + j] = acc;
        }
}

// ---------------------------------------------------------------------------
// Pass 1: project + count. Writes ONE coalesced 16B staging record per point
// {px, py, z, cell_as_bits} (cell = -1 if the point can't touch any in-image
// tap) and bumps the cell count. Later passes COPY from staging (never
// reproject), so count/fill are bit-identical by construction.
// ---------------------------------------------------------------------------
__global__ __launch_bounds__(256) void project_count_kernel(
    const float* __restrict__ depths, const float* __restrict__ Mbuf,
    float4* __restrict__ staging, int2* __restrict__ meta) {
    int gid = swizzle_block(blockIdx.x) * 256 + threadIdx.x;
    int bv = gid >> 16;
    int n = gid & (HW - 1);

    float xn = (float)(n & (W - 1)) * (2.0f / (W - 1)) - 1.0f;
    float yn = (float)(n >> 8)      * (2.0f / (H - 1)) - 1.0f;
    float d = depths[gid];
    const float* M = Mbuf + bv * 16;
    float X = xn * d, Y = yn * d;
    float p0 = M[0] * X + M[1] * Y + M[2] * d + M[3];
    float p1 = M[4] * X + M[5] * Y + M[6] * d + M[7];
    float z  = M[8] * X + M[9] * Y + M[10] * d + M[11];

    int cell = -1;
    float px = 0.0f, py = 0.0f;
    if (z > 0.0f) {  // reference masks z<=0 taps entirely
        float inv = 1.0f / (z + EPS);
        px = (p0 * inv + 1.0f) * 0.5f * (float)(W - 1);
        py = (p1 * inv + 1.0f) * 0.5f * (float)(H - 1);
        float rx = rintf(px), ry = rintf(py);
        // rounding outside the 1-px halo -> no in-image tap with weight > 0
        if (rx >= -1.0f && rx <= (float)W && ry >= -1.0f && ry <= (float)H) {
            cell = bv * (GH * GW) + ((int)ry + 1) * GW + ((int)rx + 1);
            atomicAdd(&meta[cell].y, 1);
        }
    }
    staging[gid] = make_float4(px, py, z, __int_as_float(cell));
}

// ---------------------------------------------------------------------------
// Pass 2a: block-local exclusive scan of counts. meta[i].x = local exclusive
// offset within this 256-cell block; bsum[blk] = block total. DETERMINISTIC
// (no global atomic) so the final CSR is in cell order => start(c+1)==end(c)
// for ALL cells: any cell span is one contiguous entry range.
// Covers i == NCELL (sentinel, count 0 from memset).
// ---------------------------------------------------------------------------
__global__ __launch_bounds__(256) void alloc1_kernel(int2* __restrict__ meta,
                                                     int* __restrict__ bsum) {
    int i = blockIdx.x * 256 + threadIdx.x;
    int c = (i < NCELL) ? meta[i].y : 0;
    int lane = threadIdx.x & 63;
    int wid = threadIdx.x >> 6;
    int x = c;  // inclusive scan within wave
#pragma unroll
    for (int dlt = 1; dlt < 64; dlt <<= 1) {
        int y = __shfl_up(x, dlt);
        if (lane >= dlt) x += y;
    }
    __shared__ int wsum[4];
    __shared__ int wbase[4];
    if (lane == 63) wsum[wid] = x;
    __syncthreads();
    if (threadIdx.x == 0) {
        int s0 = wsum[0], s1 = wsum[1], s2 = wsum[2], s3 = wsum[3];
        wbase[0] = 0; wbase[1] = s0; wbase[2] = s0 + s1; wbase[3] = s0 + s1 + s2;
        bsum[blockIdx.x] = s0 + s1 + s2 + s3;
    }
    __syncthreads();
    if (i <= NCELL) meta[i].x = wbase[wid] + (x - c);
}

// ---------------------------------------------------------------------------
// Pass 2b: exclusive scan of the 1561 block sums, single block, serial
// chunks of 256 with a running carry.
// ---------------------------------------------------------------------------
__global__ __launch_bounds__(256) void alloc2_kernel(int* __restrict__ bsum) {
    __shared__ int wsum[4];
    __shared__ int wbase[4];
    __shared__ int carry_s;
    int tid = threadIdx.x;
    int lane = tid & 63;
    int wid = tid >> 6;
    if (tid == 0) carry_s = 0;
    __syncthreads();
    const int nchunk = (NSUMS + 255) / 256;
    for (int ch = 0; ch < nchunk; ch++) {
        int i = ch * 256 + tid;
        int c = (i < NSUMS) ? bsum[i] : 0;
        int x = c;
#pragma unroll
        for (int dlt = 1; dlt < 64; dlt <<= 1) {
            int y = __shfl_up(x, dlt);
            if (lane >= dlt) x += y;
        }
        if (lane == 63) wsum[wid] = x;
        __syncthreads();
        if (tid == 0) {
            int cr = carry_s;
            int s0 = wsum[0], s1 = wsum[1], s2 = wsum[2], s3 = wsum[3];
            wbase[0] = cr; wbase[1] = cr + s0; wbase[2] = cr + s0 + s1;
            wbase[3] = cr + s0 + s1 + s2;
            carry_s = cr + s0 + s1 + s2 + s3;
        }
        __syncthreads();
        if (i < NSUMS) bsum[i] = wbase[wid] + (x - c);
        __syncthreads();
    }
}

// ---------------------------------------------------------------------------
// Pass 3: fill (absorbs the transpose). Per block: LDS-stage a 256-point
// feats chunk (coalesced), then each thread copies its point's staging
// record to entries16[pos] = {px,py,z, wd=exp(-tau*z)} and writes the 64B
// fp16 feature record at entriesF[pos]. pos = scanned block base + local
// atomic bump => CSR in cell order.
// ---------------------------------------------------------------------------
__global__ __launch_bounds__(256) void fill_kernel(
    const float* __restrict__ feats, const float4* __restrict__ staging,
    const int* __restrict__ bsum, int2* __restrict__ meta,
    float4* __restrict__ entries16, uint4* __restrict__ entriesF) {
    __shared__ float sm[C][257];
    int blk = blockIdx.x;
    int bv = blk >> 8;
    int n0 = (blk & 255) << 8;
    int tid = threadIdx.x;
    const float* src = feats + (size_t)bv * C * HW + n0;
#pragma unroll
    for (int c = 0; c < C; c++) sm[c][tid] = src[(size_t)c * HW + tid];
    __syncthreads();

    int gid = (bv << 16) | (n0 + tid);
    float4 s = staging[gid];
    int cell = __float_as_int(s.w);
    if (cell < 0) return;
    int pos = bsum[cell >> 8] + atomicAdd(&meta[cell].x, 1);

    float wd = expf(-TAU * s.z);  // once per point (not per tap)
    entries16[pos] = make_float4(s.x, s.y, s.z, wd);

    uint4* dst = entriesF + (size_t)pos * 4;
#pragma unroll
    for (int g = 0; g < 4; g++) {
        __half2 h0 = __floats2half2_rn(sm[g * 8 + 0][tid], sm[g * 8 + 1][tid]);
        __half2 h1 = __floats2half2_rn(sm[g * 8 + 2][tid], sm[g * 8 + 3][tid]);
        __half2 h2 = __floats2half2_rn(sm[g * 8 + 4][tid], sm[g * 8 + 5][tid]);
        __half2 h3 = __floats2half2_rn(sm[g * 8 + 6][tid], sm[g * 8 + 7][tid]);
        uint4 pk;
        pk.x = *(unsigned int*)&h0;
        pk.y = *(unsigned int*)&h1;
        pk.z = *(unsigned int*)&h2;
        pk.w = *(unsigned int*)&h3;
        dst[g] = pk;  // 64B record, 64B-aligned
    }
}

// ---------------------------------------------------------------------------
// Pass 4: TILED gather. Block = 16x16 pixel tile; its 18x18-cell halo is 18
// CONTIGUOUS CSR row-ranges (deterministic scan). Stage per-cell starts
// (18x19) + up to ROWCAP test records per row into LDS (one coalesced
// wave-load per row; exact global fallback past ROWCAP). Per thread the 3
// cells of a row collapse to ONE contiguous segment [cs[hr][lx], cs[hr][lx+3]).
// Only accepted-tap feature loads go to global.
// ---------------------------------------------------------------------------
__global__ __launch_bounds__(256) void gather_kernel(
    const float4* __restrict__ entries16, const uint4* __restrict__ entriesF,
    const int2* __restrict__ meta, const int* __restrict__ bsum,
    float* __restrict__ out) {
    __shared__ float4 lds_e[18][ROWCAP];
    __shared__ int cs_s[18][19];
    __shared__ int row_rs[18];
    __shared__ int row_stg[18];

    int sblk = swizzle_block(blockIdx.x);
    int bv = sblk >> 8;
    int t = sblk & 255;
    int ty0 = (t >> 4) << 4;   // tile origin in dest coords
    int tx0 = (t & 15) << 4;
    int tid = threadIdx.x;
    int cellbase = bv * (GH * GW);

    // Phase A: global CSR start offset for each of the 18x19 halo cells.
    // Column 18 = start of the next linear cell == end of column 17
    // (contiguity); the +1 sentinel cell (== total) covers the last span.
    for (int i = tid; i < 18 * 19; i += 256) {
        int hr = i / 19, lc = i - hr * 19;
        int cg = cellbase + (ty0 + hr) * GW + (tx0 + lc);
        int2 m = meta[cg];
        cs_s[hr][lc] = bsum[cg >> 8] + m.x - m.y;  // after fill: x=end(local)
    }
    __syncthreads();
    if (tid < 18) {
        int rs = cs_s[tid][0];
        row_rs[tid] = rs;
        row_stg[tid] = min(cs_s[tid][18] - rs, ROWCAP);
    }
    __syncthreads();
    // Phase B: stage test records, one wave per row (coalesced 16B/lane).
    {
        int wid = tid >> 6, lane = tid & 63;
        for (int hr = wid; hr < 18; hr += 4)
            if (lane < row_stg[hr])
                lds_e[hr][lane] = entries16[row_rs[hr] + lane];
    }
    __syncthreads();

    int lx = tid & 15, ly = tid >> 4;
    float qx = (float)(tx0 + lx);
    float qy = (float)(ty0 + ly);

    float wsum = 0.0f, zwsum = 0.0f;
    float facc[C];
#pragma unroll
    for (int c = 0; c < C; c++) facc[c] = 0.0f;

    auto accum = [&](float4 v, int pos) {
        float ddx = qx - v.x, ddy = qy - v.y;
        float d2 = ddx * ddx + ddy * ddy + EPS;
        if (d2 < RADIUS * RADIUS) {
            float dist = sqrtf(d2);
            float wr = 1.0f - dist * (1.0f / RADIUS);  // > 0 given d2 < R^2
            float w = wr * v.w;                        // v.w = exp(-tau*z)
            wsum += w;
            zwsum += v.z * w;
            const uint4* fp = entriesF + (size_t)pos * 4;
#pragma unroll
            for (int g = 0; g < 4; g++) {
                uint4 fv = fp[g];
                const __half2* h2 = (const __half2*)&fv;
#pragma unroll
                for (int k = 0; k < 4; k++) {
                    float2 f2 = __half22float2(h2[k]);
                    facc[g * 8 + 2 * k]     = fmaf(w, f2.x, facc[g * 8 + 2 * k]);
                    facc[g * 8 + 2 * k + 1] = fmaf(w, f2.y, facc[g * 8 + 2 * k + 1]);
                }
            }
        }
    };

#pragma unroll
    for (int dy = 0; dy < 3; dy++) {
        int hr = ly + dy;
        int s = cs_s[hr][lx];
        int e = cs_s[hr][lx + 3];
        int rs = row_rs[hr];
        int se = rs + row_stg[hr];
        int e1 = min(e, se);
        for (int pos = s; pos < e1; ++pos)          // LDS fast path
            accum(lds_e[hr][pos - rs], pos);
        for (int pos = max(s, se); pos < e; ++pos)  // exact overflow fallback
            accum(entries16[pos], pos);
    }

    int q = ((ty0 + ly) << 8) | (tx0 + lx);
    int gid = (bv << 16) | q;
    float invw = 1.0f / (wsum + EPS);
    float* ob = out + (size_t)bv * C * HW + q;
#pragma unroll
    for (int c = 0; c < C; c++) ob[(size_t)c * HW] = facc[c] * invw;
    out[(size_t)BV * C * HW + gid] = zwsum * invw;
}

extern "C" void kernel_launch(void* const* d_in, const int* in_sizes, int n_in,
                              void* d_out, int out_size, void* d_ws, size_t ws_size,
                              hipStream_t stream) {
    const float* depths   = (const float*)d_in[0];  // (B,V,1,H,W)
    const float* feats    = (const float*)d_in[1];  // (B,V,C,H,W)
    const float* Kmat     = (const float*)d_in[2];  // (B,4,4)
    const float* srcRTinv = (const float*)d_in[4];  // (B,V,4,4)
    const float* dstRT    = (const float*)d_in[5];  // (B,1,4,4)
    float* out = (float*)d_out;

    // ws layout:
    //   entriesF  : NPIX * 64B fp16 records (CSR pos-indexed)  25.17 MB
    //   entries16 : NPIX * float4 {px,py,z,wd}                  6.29 MB
    //   staging   : NPIX * float4 {px,py,z,cell}                6.29 MB
    //   meta      : (NCELL+1) int2 {ofs,cnt}                    3.20 MB
    //   bsum      : NSUMS int                                   6.2 KB
    //   Mbuf      : BV*16 float                                 tiny
    // total ~41 MB (<= 63 MB proven available)
    char* ws = (char*)d_ws;
    size_t off_entriesF = 0;
    size_t off_entries16 = off_entriesF + (size_t)NPIX * 64;
    size_t off_staging = off_entries16 + (size_t)NPIX * 16;
    size_t off_meta = off_staging + (size_t)NPIX * 16;
    size_t off_bsum = off_meta + (size_t)(NCELL + 1) * 8;
    size_t off_M = off_bsum + (size_t)NSUMS * 4 + 16;
    size_t needed = off_M + (size_t)BV * 16 * 4;

    if (ws_size < needed) {
        hipMemsetAsync(d_out, 0, (size_t)out_size * 4, stream);
        return;
    }

    uint4* entriesF   = (uint4*)(ws + off_entriesF);
    float4* entries16 = (float4*)(ws + off_entries16);
    float4* staging   = (float4*)(ws + off_staging);
    int2* meta        = (int2*)(ws + off_meta);
    int* bsum         = (int*)(ws + off_bsum);
    float* Mbuf       = (float*)(ws + off_M);

    // zero meta {ofs,cnt} incl. sentinel (bsum fully written by alloc1)
    hipMemsetAsync(meta, 0, (size_t)(NCELL + 1) * 8, stream);
    setup_kernel<<<1, 64, 0, stream>>>(Kmat, srcRTinv, dstRT, Mbuf);
    project_count_kernel<<<NBLK, 256, 0, stream>>>(depths, Mbuf, staging, meta);
    alloc1_kernel<<<NSUMS, 256, 0, stream>>>(meta, bsum);
    alloc2_kernel<<<1, 256, 0, stream>>>(bsum);
    fill_kernel<<<NBLK, 256, 0, stream>>>(feats, staging, bsum, meta,
                                          entries16, entriesF);
    gather_kernel<<<NBLK, 256, 0, stream>>>(entries16, entriesF, meta, bsum,
                                            out);
}

// Round 7
// 183.645 us; speedup vs baseline: 1.4772x; 1.0016x over previous
//
#include <hip/hip_runtime.h>
#include <hip/hip_fp16.h>
#include <math.h>

#define H 256
#define W 256
#define HW (H * W)
#define B 2
#define V 3
#define BV (B * V)
#define C 32
#define RADIUS 1.5f
#define TAU 1.0f
#define EPS 1e-8f

#define NPIX (BV * HW)    // 393216 destination pixels (= source points)
#define NBLK (NPIX / 256) // 1536 (divisible by 8 -> bijective XCD swizzle)

// Cell grid: one bin per ROUNDED projected position, 1-pixel halo.
#define GW 258
#define GH 258
#define NCELL (BV * GH * GW)           // 399384 cells (+1 sentinel)
#define NSUMS ((NCELL + 255) / 256)    // 1561 alloc blocks
#define ECAP 384                       // staged entries per tile halo (mean ~295)

// XCD-aware chunked swizzle (NBLK divisible by 8 -> bijective).
__device__ __forceinline__ int swizzle_block(int bid) {
    return (bid & 7) * (NBLK / 8) + (bid >> 3);
}

// ---------------------------------------------------------------------------
// Setup: per (b,v) fold the projection chain into one matrix
//   M = K[b] * dst_RT[b] * src_RTinv[b,v] * inv(K[b])
// ---------------------------------------------------------------------------
__global__ void setup_kernel(const float* __restrict__ Kmat,
                             const float* __restrict__ srcRTinv,
                             const float* __restrict__ dstRT,
                             float* __restrict__ Mbuf) {
    int bv = threadIdx.x;
    if (bv >= BV) return;
    int b = bv / V;

    float a[4][8];
    for (int i = 0; i < 4; i++)
        for (int j = 0; j < 4; j++) {
            a[i][j] = Kmat[b * 16 + i * 4 + j];
            a[i][4 + j] = (i == j) ? 1.0f : 0.0f;
        }
    for (int col = 0; col < 4; col++) {
        int piv = col;
        float best = fabsf(a[col][col]);
        for (int r = col + 1; r < 4; r++) {
            float v = fabsf(a[r][col]);
            if (v > best) { best = v; piv = r; }
        }
        if (piv != col) {
            for (int j = 0; j < 8; j++) {
                float t = a[col][j]; a[col][j] = a[piv][j]; a[piv][j] = t;
            }
        }
        float s = 1.0f / a[col][col];
        for (int j = 0; j < 8; j++) a[col][j] *= s;
        for (int r = 0; r < 4; r++) {
            if (r == col) continue;
            float m = a[r][col];
            for (int j = 0; j < 8; j++) a[r][j] -= m * a[col][j];
        }
    }
    float Kinv[16];
    for (int i = 0; i < 4; i++)
        for (int j = 0; j < 4; j++) Kinv[i * 4 + j] = a[i][4 + j];

    float T1[16];
    const float* S = srcRTinv + bv * 16;
    for (int i = 0; i < 4; i++)
        for (int j = 0; j < 4; j++) {
            float acc = 0.0f;
            for (int k = 0; k < 4; k++) acc += S[i * 4 + k] * Kinv[k * 4 + j];
            T1[i * 4 + j] = acc;
        }
    float T2[16];
    const float* D = dstRT + b * 16;
    for (int i = 0; i < 4; i++)
        for (int j = 0; j < 4; j++) {
            float acc = 0.0f;
            for (int k = 0; k < 4; k++) acc += D[i * 4 + k] * T1[k * 4 + j];
            T2[i * 4 + j] = acc;
        }
    const float* Kb = Kmat + b * 16;
    for (int i = 0; i < 4; i++)
        for (int j = 0; j < 4; j++) {
            float acc = 0.0f;
            for (int k = 0; k < 4; k++) acc += Kb[i * 4 + k] * T2[k * 4 + j];
            Mbuf[bv * 16 + i * 4 + j] = acc;
        }
}

// ---------------------------------------------------------------------------
// Pass 1: project + count. Writes ONE coalesced 16B staging record per point
// {px, py, z, cell_as_bits} (cell = -1 if the point can't touch any in-image
// tap) and bumps the cell count. Later passes COPY from staging (never
// reproject), so count/fill are bit-identical by construction.
// ---------------------------------------------------------------------------
__global__ __launch_bounds__(256) void project_count_kernel(
    const float* __restrict__ depths, const float* __restrict__ Mbuf,
    float4* __restrict__ staging, int2* __restrict__ meta) {
    int gid = swizzle_block(blockIdx.x) * 256 + threadIdx.x;
    int bv = gid >> 16;
    int n = gid & (HW - 1);

    float xn = (float)(n & (W - 1)) * (2.0f / (W - 1)) - 1.0f;
    float yn = (float)(n >> 8)      * (2.0f / (H - 1)) - 1.0f;
    float d = depths[gid];
    const float* M = Mbuf + bv * 16;
    float X = xn * d, Y = yn * d;
    float p0 = M[0] * X + M[1] * Y + M[2] * d + M[3];
    float p1 = M[4] * X + M[5] * Y + M[6] * d + M[7];
    float z  = M[8] * X + M[9] * Y + M[10] * d + M[11];

    int cell = -1;
    float px = 0.0f, py = 0.0f;
    if (z > 0.0f) {  // reference masks z<=0 taps entirely
        float inv = 1.0f / (z + EPS);
        px = (p0 * inv + 1.0f) * 0.5f * (float)(W - 1);
        py = (p1 * inv + 1.0f) * 0.5f * (float)(H - 1);
        float rx = rintf(px), ry = rintf(py);
        // rounding outside the 1-px halo -> no in-image tap with weight > 0
        if (rx >= -1.0f && rx <= (float)W && ry >= -1.0f && ry <= (float)H) {
            cell = bv * (GH * GW) + ((int)ry + 1) * GW + ((int)rx + 1);
            atomicAdd(&meta[cell].y, 1);
        }
    }
    staging[gid] = make_float4(px, py, z, __int_as_float(cell));
}

// ---------------------------------------------------------------------------
// Pass 2a: block-local exclusive scan of counts. meta[i].x = local exclusive
// offset within this 256-cell block; bsum[blk] = block total. DETERMINISTIC
// (no global atomic) so the final CSR is in cell order => start(c+1)==end(c)
// for ALL cells: any cell span is one contiguous entry range.
// Covers i == NCELL (sentinel, count 0 from memset).
// ---------------------------------------------------------------------------
__global__ __launch_bounds__(256) void alloc1_kernel(int2* __restrict__ meta,
                                                     int* __restrict__ bsum) {
    int i = blockIdx.x * 256 + threadIdx.x;
    int c = (i < NCELL) ? meta[i].y : 0;
    int lane = threadIdx.x & 63;
    int wid = threadIdx.x >> 6;
    int x = c;  // inclusive scan within wave
#pragma unroll
    for (int dlt = 1; dlt < 64; dlt <<= 1) {
        int y = __shfl_up(x, dlt);
        if (lane >= dlt) x += y;
    }
    __shared__ int wsum[4];
    __shared__ int wbase[4];
    if (lane == 63) wsum[wid] = x;
    __syncthreads();
    if (threadIdx.x == 0) {
        int s0 = wsum[0], s1 = wsum[1], s2 = wsum[2], s3 = wsum[3];
        wbase[0] = 0; wbase[1] = s0; wbase[2] = s0 + s1; wbase[3] = s0 + s1 + s2;
        bsum[blockIdx.x] = s0 + s1 + s2 + s3;
    }
    __syncthreads();
    if (i <= NCELL) meta[i].x = wbase[wid] + (x - c);
}

// ---------------------------------------------------------------------------
// Pass 2b: exclusive scan of the 1561 block sums, single block, serial
// chunks of 256 with a running carry.
// ---------------------------------------------------------------------------
__global__ __launch_bounds__(256) void alloc2_kernel(int* __restrict__ bsum) {
    __shared__ int wsum[4];
    __shared__ int wbase[4];
    __shared__ int carry_s;
    int tid = threadIdx.x;
    int lane = tid & 63;
    int wid = tid >> 6;
    if (tid == 0) carry_s = 0;
    __syncthreads();
    const int nchunk = (NSUMS + 255) / 256;
    for (int ch = 0; ch < nchunk; ch++) {
        int i = ch * 256 + tid;
        int c = (i < NSUMS) ? bsum[i] : 0;
        int x = c;
#pragma unroll
        for (int dlt = 1; dlt < 64; dlt <<= 1) {
            int y = __shfl_up(x, dlt);
            if (lane >= dlt) x += y;
        }
        if (lane == 63) wsum[wid] = x;
        __syncthreads();
        if (tid == 0) {
            int cr = carry_s;
            int s0 = wsum[0], s1 = wsum[1], s2 = wsum[2], s3 = wsum[3];
            wbase[0] = cr; wbase[1] = cr + s0; wbase[2] = cr + s0 + s1;
            wbase[3] = cr + s0 + s1 + s2;
            carry_s = cr + s0 + s1 + s2 + s3;
        }
        __syncthreads();
        if (i < NSUMS) bsum[i] = wbase[wid] + (x - c);
        __syncthreads();
    }
}

// ---------------------------------------------------------------------------
// Pass 3: fill (absorbs the transpose). Per block: LDS-stage a 256-point
// feats chunk (coalesced), then each thread copies its point's staging
// record to entries16[pos] = {px,py,z, wd=exp(-tau*z)} and writes the 64B
// fp16 feature record at entriesF[pos]. pos = scanned block base + local
// atomic bump => CSR in cell order.
// ---------------------------------------------------------------------------
__global__ __launch_bounds__(256) void fill_kernel(
    const float* __restrict__ feats, const float4* __restrict__ staging,
    const int* __restrict__ bsum, int2* __restrict__ meta,
    float4* __restrict__ entries16, uint4* __restrict__ entriesF) {
    __shared__ float sm[C][257];
    int blk = blockIdx.x;
    int bv = blk >> 8;
    int n0 = (blk & 255) << 8;
    int tid = threadIdx.x;
    const float* src = feats + (size_t)bv * C * HW + n0;
#pragma unroll
    for (int c = 0; c < C; c++) sm[c][tid] = src[(size_t)c * HW + tid];
    __syncthreads();

    int gid = (bv << 16) | (n0 + tid);
    float4 s = staging[gid];
    int cell = __float_as_int(s.w);
    if (cell < 0) return;
    int pos = bsum[cell >> 8] + atomicAdd(&meta[cell].x, 1);

    float wd = expf(-TAU * s.z);  // once per point (not per tap)
    entries16[pos] = make_float4(s.x, s.y, s.z, wd);

    uint4* dst = entriesF + (size_t)pos * 4;
#pragma unroll
    for (int g = 0; g < 4; g++) {
        __half2 h0 = __floats2half2_rn(sm[g * 8 + 0][tid], sm[g * 8 + 1][tid]);
        __half2 h1 = __floats2half2_rn(sm[g * 8 + 2][tid], sm[g * 8 + 3][tid]);
        __half2 h2 = __floats2half2_rn(sm[g * 8 + 4][tid], sm[g * 8 + 5][tid]);
        __half2 h3 = __floats2half2_rn(sm[g * 8 + 6][tid], sm[g * 8 + 7][tid]);
        uint4 pk;
        pk.x = *(unsigned int*)&h0;
        pk.y = *(unsigned int*)&h1;
        pk.z = *(unsigned int*)&h2;
        pk.w = *(unsigned int*)&h3;
        dst[g] = pk;  // 64B record, 64B-aligned
    }
}

// ---------------------------------------------------------------------------
// Pass 4: TILED gather v3. Block = 16x16 pixel tile; its 18 halo rows are 18
// contiguous CSR ranges. Stage per-cell starts AND the test records AND the
// fp16 FEATURE records into LDS (compact-packed, coalesced 1KB/wave-inst
// staging loads; mean ~295 entries, cap ECAP=384, exact global fallback).
// Feature LDS stride = 5 uint4 (80B) so entry-indexed ds_read_b128 spreads
// across all 32 banks. Per accepted tap everything is an LDS read; the only
// per-thread global traffic left is the out write.
// ---------------------------------------------------------------------------
__global__ __launch_bounds__(256) void gather_kernel(
    const float4* __restrict__ entries16, const uint4* __restrict__ entriesF,
    const int2* __restrict__ meta, const int* __restrict__ bsum,
    float* __restrict__ out) {
    __shared__ int cs_s[18][19];
    __shared__ int row_rs[18];   // global CSR start of row
    __shared__ int row_off[18];  // compact LDS offset of row
    __shared__ int row_sl[18];   // staged length of row
    __shared__ float4 lds_e[ECAP];
    __shared__ uint4 lds_f[ECAP * 5];  // [idx*5 + g], g in 0..3 (pad slot 4)

    int sblk = swizzle_block(blockIdx.x);
    int bv = sblk >> 8;
    int t = sblk & 255;
    int ty0 = (t >> 4) << 4;   // tile origin in dest coords
    int tx0 = (t & 15) << 4;
    int tid = threadIdx.x;
    int cellbase = bv * (GH * GW);

    // Phase A: global CSR start offset for each of the 18x19 halo cells.
    // Column 18 = start of the next linear cell == end of column 17
    // (contiguity); the +1 sentinel cell (== total) covers the last span.
    for (int i = tid; i < 18 * 19; i += 256) {
        int hr = i / 19, lc = i - hr * 19;
        int cg = cellbase + (ty0 + hr) * GW + (tx0 + lc);
        int2 m = meta[cg];
        cs_s[hr][lc] = bsum[cg >> 8] + m.x - m.y;  // after fill: x=end(local)
    }
    __syncthreads();
    // Phase A2: compact packing offsets (serial over 18 rows, trivial).
    if (tid == 0) {
        int off = 0;
        for (int hr = 0; hr < 18; hr++) {
            int rs = cs_s[hr][0];
            int len = cs_s[hr][18] - rs;
            int sl = min(len, ECAP - off);
            if (sl < 0) sl = 0;
            row_rs[hr] = rs;
            row_off[hr] = off;
            row_sl[hr] = sl;
            off += sl;
        }
    }
    __syncthreads();
    // Phase B: stage test + feature records; wave w handles rows w, w+4, ...
    {
        int wid = tid >> 6, lane = tid & 63;
        for (int hr = wid; hr < 18; hr += 4) {
            int rs = row_rs[hr], off = row_off[hr], sl = row_sl[hr];
            for (int j = lane; j < sl; j += 64)
                lds_e[off + j] = entries16[rs + j];
            int j0 = lane >> 2, g = lane & 3;
            for (int j = j0; j < sl; j += 16)  // 64 lanes = 1KB contiguous
                lds_f[(off + j) * 5 + g] = entriesF[(size_t)(rs + j) * 4 + g];
        }
    }
    __syncthreads();

    int lx = tid & 15, ly = tid >> 4;
    float qx = (float)(tx0 + lx);
    float qy = (float)(ty0 + ly);

    float wsum = 0.0f, zwsum = 0.0f;
    float facc[C];
#pragma unroll
    for (int c = 0; c < C; c++) facc[c] = 0.0f;

    auto accum_lds = [&](float4 v, int li) {
        float ddx = qx - v.x, ddy = qy - v.y;
        float d2 = ddx * ddx + ddy * ddy + EPS;
        if (d2 < RADIUS * RADIUS) {
            float dist = sqrtf(d2);
            float wr = 1.0f - dist * (1.0f / RADIUS);
            float w = wr * v.w;  // v.w = exp(-tau*z)
            wsum += w;
            zwsum += v.z * w;
#pragma unroll
            for (int g = 0; g < 4; g++) {
                uint4 fv = lds_f[li * 5 + g];
                const __half2* h2 = (const __half2*)&fv;
#pragma unroll
                for (int k = 0; k < 4; k++) {
                    float2 f2 = __half22float2(h2[k]);
                    facc[g * 8 + 2 * k]     = fmaf(w, f2.x, facc[g * 8 + 2 * k]);
                    facc[g * 8 + 2 * k + 1] = fmaf(w, f2.y, facc[g * 8 + 2 * k + 1]);
                }
            }
        }
    };
    auto accum_glb = [&](float4 v, int pos) {
        float ddx = qx - v.x, ddy = qy - v.y;
        float d2 = ddx * ddx + ddy * ddy + EPS;
        if (d2 < RADIUS * RADIUS) {
            float dist = sqrtf(d2);
            float wr = 1.0f - dist * (1.0f / RADIUS);
            float w = wr * v.w;
            wsum += w;
            zwsum += v.z * w;
            const uint4* fp = entriesF + (size_t)pos * 4;
#pragma unroll
            for (int g = 0; g < 4; g++) {
                uint4 fv = fp[g];
                const __half2* h2 = (const __half2*)&fv;
#pragma unroll
                for (int k = 0; k < 4; k++) {
                    float2 f2 = __half22float2(h2[k]);
                    facc[g * 8 + 2 * k]     = fmaf(w, f2.x, facc[g * 8 + 2 * k]);
                    facc[g * 8 + 2 * k + 1] = fmaf(w, f2.y, facc[g * 8 + 2 * k + 1]);
                }
            }
        }
    };

#pragma unroll
    for (int dy = 0; dy < 3; dy++) {
        int hr = ly + dy;
        int s = cs_s[hr][lx];
        int e = cs_s[hr][lx + 3];
        int rs = row_rs[hr];
        int off = row_off[hr];
        int sEnd = rs + row_sl[hr];
        int e1 = min(e, sEnd);
        for (int pos = s; pos < e1; ++pos) {        // LDS fast path
            int li = off + (pos - rs);
            accum_lds(lds_e[li], li);
        }
        for (int pos = max(s, sEnd); pos < e; ++pos)  // exact overflow fallback
            accum_glb(entries16[pos], pos);
    }

    int q = ((ty0 + ly) << 8) | (tx0 + lx);
    int gid = (bv << 16) | q;
    float invw = 1.0f / (wsum + EPS);
    float* ob = out + (size_t)bv * C * HW + q;
#pragma unroll
    for (int c = 0; c < C; c++) ob[(size_t)c * HW] = facc[c] * invw;
    out[(size_t)BV * C * HW + gid] = zwsum * invw;
}

extern "C" void kernel_launch(void* const* d_in, const int* in_sizes, int n_in,
                              void* d_out, int out_size, void* d_ws, size_t ws_size,
                              hipStream_t stream) {
    const float* depths   = (const float*)d_in[0];  // (B,V,1,H,W)
    const float* feats    = (const float*)d_in[1];  // (B,V,C,H,W)
    const float* Kmat     = (const float*)d_in[2];  // (B,4,4)
    const float* srcRTinv = (const float*)d_in[4];  // (B,V,4,4)
    const float* dstRT    = (const float*)d_in[5];  // (B,1,4,4)
    float* out = (float*)d_out;

    // ws layout:
    //   entriesF  : NPIX * 64B fp16 records (CSR pos-indexed)  25.17 MB
    //   entries16 : NPIX * float4 {px,py,z,wd}                  6.29 MB
    //   staging   : NPIX * float4 {px,py,z,cell}                6.29 MB
    //   meta      : (NCELL+1) int2 {ofs,cnt}                    3.20 MB
    //   bsum      : NSUMS int                                   6.2 KB
    //   Mbuf      : BV*16 float                                 tiny
    // total ~41 MB (<= 63 MB proven available)
    char* ws = (char*)d_ws;
    size_t off_entriesF = 0;
    size_t off_entries16 = off_entriesF + (size_t)NPIX * 64;
    size_t off_staging = off_entries16 + (size_t)NPIX * 16;
    size_t off_meta = off_staging + (size_t)NPIX * 16;
    size_t off_bsum = off_meta + (size_t)(NCELL + 1) * 8;
    size_t off_M = off_bsum + (size_t)NSUMS * 4 + 16;
    size_t needed = off_M + (size_t)BV * 16 * 4;

    if (ws_size < needed) {
        hipMemsetAsync(d_out, 0, (size_t)out_size * 4, stream);
        return;
    }

    uint4* entriesF   = (uint4*)(ws + off_entriesF);
    float4* entries16 = (float4*)(ws + off_entries16);
    float4* staging   = (float4*)(ws + off_staging);
    int2* meta        = (int2*)(ws + off_meta);
    int* bsum         = (int*)(ws + off_bsum);
    float* Mbuf       = (float*)(ws + off_M);

    // zero meta {ofs,cnt} incl. sentinel (bsum fully written by alloc1)
    hipMemsetAsync(meta, 0, (size_t)(NCELL + 1) * 8, stream);
    setup_kernel<<<1, 64, 0, stream>>>(Kmat, srcRTinv, dstRT, Mbuf);
    project_count_kernel<<<NBLK, 256, 0, stream>>>(depths, Mbuf, staging, meta);
    alloc1_kernel<<<NSUMS, 256, 0, stream>>>(meta, bsum);
    alloc2_kernel<<<1, 256, 0, stream>>>(bsum);
    fill_kernel<<<NBLK, 256, 0, stream>>>(feats, staging, bsum, meta,
                                          entries16, entriesF);
    gather_kernel<<<NBLK, 256, 0, stream>>>(entries16, entriesF, meta, bsum,
                                            out);
}